// Round 3
// baseline (152.707 us; speedup 1.0000x reference)
//
#include <hip/hip_runtime.h>

#define KS    7
#define H     256
#define W     256
#define STRIP 16                 // output rows per wave
#define WPB   4                  // waves per block (block covers 64 rows)
#define NSTEP (STRIP + KS - 1)   // 22 input rows per strip

// Build effective 7x7 kernel: w_eff = mk + noise*(noise_eps - mean(noise_eps))
__global__ void GaussianConvBlur_wprep(const float* __restrict__ weight,
                                       const float* __restrict__ noise,
                                       const float* __restrict__ noise_eps,
                                       float* __restrict__ wf) {
    int tid = threadIdx.x;
    if (tid < KS * KS) {
        float m = 0.f;
        #pragma unroll
        for (int i = 0; i < KS * KS; ++i) m += noise_eps[i];
        m *= (1.0f / (KS * KS));
        wf[tid] = weight[tid] + noise[0] * (noise_eps[tid] - m);
    }
}

// LDS-free depthwise 7x7, ring-8 accumulators, software-pipelined row loads.
__global__ __launch_bounds__(256) void GaussianConvBlur_conv(
        const float* __restrict__ in,
        const float* __restrict__ wfg,
        float* __restrict__ out) {
    const int lane = threadIdx.x & 63;
    const int wid  = threadIdx.x >> 6;

    const int plane = blockIdx.x >> 2;          // 4 blocks per plane
    const int sblk  = blockIdx.x & 3;
    const int s0    = (sblk * WPB + wid) * STRIP;

    const float* __restrict__ src = in  + (size_t)plane * (H * W);
    float*       __restrict__ dst = out + (size_t)plane * (H * W);

    // Pin the 49 uniform weights to SGPRs
    float wf[KS * KS];
    #pragma unroll
    for (int i = 0; i < KS * KS; ++i)
        wf[i] = __int_as_float(__builtin_amdgcn_readfirstlane(__float_as_int(wfg[i])));

    const int x4 = lane << 2;

    float4 acc[8];
    #pragma unroll
    for (int i = 0; i < 8; ++i) acc[i] = make_float4(0.f, 0.f, 0.f, 0.f);

    float4 nb1[2];   // double-buffered prefetch of the aligned row load

    // prefetch: clamped row address is always valid -> load issues early
    #define LOADROW(REL, P) do {                                          \
        int ri_  = s0 - 3 + (REL);                                        \
        int ric_ = ri_ < 0 ? 0 : (ri_ > (H - 1) ? (H - 1) : ri_);         \
        nb1[P] = *(const float4*)(src + ric_ * W + x4);                   \
    } while (0)

    #define STEPBODY(REL, U, PF) do {                                     \
        if (PF) LOADROW((REL) + 1, ((U) + 1) & 1);                        \
        const int ri = s0 - 3 + (REL);                                    \
        if (ri >= 0 && ri < H) {          /* valid row: accumulate */     \
            const float* rowp_ = src + ri * W + x4;                       \
            float4 r1 = nb1[(U) & 1];                                     \
            float4 r0 = make_float4(0.f, 0.f, 0.f, 0.f);                  \
            float4 r2 = make_float4(0.f, 0.f, 0.f, 0.f);                  \
            if (lane > 0)  r0 = *(const float4*)(rowp_ - 4);  /* L1 hit */\
            if (lane < 63) r2 = *(const float4*)(rowp_ + 4);  /* L1 hit */\
            float s[10];                                                  \
            s[0] = r0.y; s[1] = r0.z; s[2] = r0.w;                        \
            s[3] = r1.x; s[4] = r1.y; s[5] = r1.z; s[6] = r1.w;           \
            s[7] = r2.x; s[8] = r2.y; s[9] = r2.z;                        \
            _Pragma("unroll")                                             \
            for (int j = 0; j < 7; ++j) {                                 \
                const int slot = ((U) + j) & 7;    /* compile-time */     \
                const int ky   = 6 - j;                                   \
                _Pragma("unroll")                                         \
                for (int kx = 0; kx < 7; ++kx) {                          \
                    const float wv = wf[ky * 7 + kx];                     \
                    acc[slot].x = fmaf(wv, s[kx],     acc[slot].x);       \
                    acc[slot].y = fmaf(wv, s[kx + 1], acc[slot].y);       \
                    acc[slot].z = fmaf(wv, s[kx + 2], acc[slot].z);       \
                    acc[slot].w = fmaf(wv, s[kx + 3], acc[slot].w);       \
                }                                                         \
            }                                                             \
        }                                                                 \
        const int o = ri - 3;            /* this row completes now */     \
        if (o >= s0) *(float4*)(dst + o * W + x4) = acc[(U) & 7];         \
        acc[(U) & 7] = make_float4(0.f, 0.f, 0.f, 0.f);                   \
    } while (0)

    LOADROW(0, 0);

    for (int g = 0; g < 2; ++g) {         // rel = 0..15
        #pragma unroll
        for (int u = 0; u < 8; ++u) STEPBODY(g * 8 + u, u, true);
    }
    #pragma unroll
    for (int u = 0; u < 6; ++u)           // rel = 16..21
        STEPBODY(16 + u, u, (u < 5));

    #undef LOADROW
    #undef STEPBODY
}

extern "C" void kernel_launch(void* const* d_in, const int* in_sizes, int n_in,
                              void* d_out, int out_size, void* d_ws, size_t ws_size,
                              hipStream_t stream) {
    const float* x         = (const float*)d_in[0];  // (16,64,256,256)
    const float* weight    = (const float*)d_in[1];  // (64,64,7,7)
    const float* noise     = (const float*)d_in[2];  // scalar
    const float* noise_eps = (const float*)d_in[3];  // (7,7)
    float*       out       = (float*)d_out;
    float*       wf        = (float*)d_ws;           // 49 floats scratch

    GaussianConvBlur_wprep<<<1, 64, 0, stream>>>(weight, noise, noise_eps, wf);

    const int planes = 16 * 64;                       // 1024 planes
    GaussianConvBlur_conv<<<planes * 4, 256, 0, stream>>>(x, wf, out);
}

// Round 4
// 128.913 us; speedup vs baseline: 1.1846x; 1.1846x over previous
//
#include <hip/hip_runtime.h>

#define KS    7
#define H     256
#define W     256
#define STRIP 32                 // output rows per wave
#define WPB   4                  // waves per block (block covers 128 rows)
#define NSTEP (STRIP + KS - 1)   // 38 input rows per strip

// Build effective 7x7 kernel: w_eff = mk + noise*(noise_eps - mean(noise_eps))
__global__ void GaussianConvBlur_wprep(const float* __restrict__ weight,
                                       const float* __restrict__ noise,
                                       const float* __restrict__ noise_eps,
                                       float* __restrict__ wf) {
    int tid = threadIdx.x;
    if (tid < KS * KS) {
        float m = 0.f;
        #pragma unroll
        for (int i = 0; i < KS * KS; ++i) m += noise_eps[i];
        m *= (1.0f / (KS * KS));
        wf[tid] = weight[tid] + noise[0] * (noise_eps[tid] - m);
    }
}

// LDS-free depthwise 7x7: ring-8 fp32 accumulators, ALL row loads (aligned +
// both halos) prefetched one step ahead with clamped, always-valid addresses.
__global__ __launch_bounds__(256) void GaussianConvBlur_conv(
        const float* __restrict__ in,
        const float* __restrict__ wfg,
        float* __restrict__ out) {
    const int lane = threadIdx.x & 63;
    const int wid  = threadIdx.x >> 6;

    const int plane = blockIdx.x >> 1;          // 2 blocks per plane
    const int sblk  = blockIdx.x & 1;
    const int s0    = __builtin_amdgcn_readfirstlane((sblk * WPB + wid) * STRIP);

    const float* __restrict__ src = in  + (size_t)plane * (H * W);
    float*       __restrict__ dst = out + (size_t)plane * (H * W);

    // Pin the 49 uniform weights to SGPRs
    float wf[KS * KS];
    #pragma unroll
    for (int i = 0; i < KS * KS; ++i)
        wf[i] = __int_as_float(__builtin_amdgcn_readfirstlane(__float_as_int(wfg[i])));

    const int x4 = lane << 2;                   // aligned offset (floats)
    const int xl = lane ? x4 - 4 : 0;           // clamped left-halo offset
    const int xr = (lane < 63) ? x4 + 4 : x4;   // clamped right-halo offset
    const bool ln0  = (lane == 0);
    const bool ln63 = (lane == 63);

    float4 acc[8];
    #pragma unroll
    for (int i = 0; i < 8; ++i) acc[i] = make_float4(0.f, 0.f, 0.f, 0.f);

    float4 pm[2], pl[2], pr[2];                 // double-buffered prefetch

    #define LOADROW(REL, P) do {                                          \
        int ri_  = s0 - 3 + (REL);                                        \
        int ric_ = ri_ < 0 ? 0 : (ri_ > (H - 1) ? (H - 1) : ri_);         \
        const float* rb_ = src + ric_ * W;                                \
        pm[P] = *(const float4*)(rb_ + x4);                               \
        pl[P] = *(const float4*)(rb_ + xl);                               \
        pr[P] = *(const float4*)(rb_ + xr);                               \
    } while (0)

    #define STEPBODY(REL, U, PF) do {                                     \
        if (PF) LOADROW((REL) + 1, ((U) + 1) & 1);                        \
        const int ri = s0 - 3 + (REL);        /* uniform (SGPR) */        \
        if (ri >= 0 && ri < H) {              /* valid row: accumulate */ \
            float4 r1 = pm[(U) & 1];                                      \
            float4 r0 = pl[(U) & 1];                                      \
            float4 r2 = pr[(U) & 1];                                      \
            float s[10];                                                  \
            s[0] = ln0  ? 0.f : r0.y;                                     \
            s[1] = ln0  ? 0.f : r0.z;                                     \
            s[2] = ln0  ? 0.f : r0.w;                                     \
            s[3] = r1.x; s[4] = r1.y; s[5] = r1.z; s[6] = r1.w;           \
            s[7] = ln63 ? 0.f : r2.x;                                     \
            s[8] = ln63 ? 0.f : r2.y;                                     \
            s[9] = ln63 ? 0.f : r2.z;                                     \
            _Pragma("unroll")                                             \
            for (int j = 0; j < 7; ++j) {                                 \
                const int slot = ((U) + j) & 7;    /* compile-time */     \
                const int ky   = 6 - j;                                   \
                _Pragma("unroll")                                         \
                for (int kx = 0; kx < 7; ++kx) {                          \
                    const float wv = wf[ky * 7 + kx];                     \
                    acc[slot].x = fmaf(wv, s[kx],     acc[slot].x);       \
                    acc[slot].y = fmaf(wv, s[kx + 1], acc[slot].y);       \
                    acc[slot].z = fmaf(wv, s[kx + 2], acc[slot].z);       \
                    acc[slot].w = fmaf(wv, s[kx + 3], acc[slot].w);       \
                }                                                         \
            }                                                             \
        }                                                                 \
        const int o = ri - 3;            /* this row completes now */     \
        if (o >= s0) *(float4*)(dst + o * W + x4) = acc[(U) & 7];         \
        acc[(U) & 7] = make_float4(0.f, 0.f, 0.f, 0.f);                   \
    } while (0)

    LOADROW(0, 0);

    for (int g = 0; g < 4; ++g) {         // rel = 0..31
        #pragma unroll
        for (int u = 0; u < 8; ++u) STEPBODY(g * 8 + u, u, true);
    }
    #pragma unroll
    for (int u = 0; u < 6; ++u)           // rel = 32..37
        STEPBODY(32 + u, u, (u < 5));

    #undef LOADROW
    #undef STEPBODY
}

extern "C" void kernel_launch(void* const* d_in, const int* in_sizes, int n_in,
                              void* d_out, int out_size, void* d_ws, size_t ws_size,
                              hipStream_t stream) {
    const float* x         = (const float*)d_in[0];  // (16,64,256,256)
    const float* weight    = (const float*)d_in[1];  // (64,64,7,7)
    const float* noise     = (const float*)d_in[2];  // scalar
    const float* noise_eps = (const float*)d_in[3];  // (7,7)
    float*       out       = (float*)d_out;
    float*       wf        = (float*)d_ws;           // 49 floats scratch

    GaussianConvBlur_wprep<<<1, 64, 0, stream>>>(weight, noise, noise_eps, wf);

    const int planes = 16 * 64;                       // 1024 planes
    GaussianConvBlur_conv<<<planes * 2, 256, 0, stream>>>(x, wf, out);
}

// Round 5
// 118.966 us; speedup vs baseline: 1.2836x; 1.0836x over previous
//
#include <hip/hip_runtime.h>

#define KS    7
#define H     256
#define W     256
#define STRIP 16                 // output rows per wave
#define WPB   4                  // waves per block (block covers 64 rows)
#define NSTEP (STRIP + KS - 1)   // 22 input rows per strip

// Build effective 7x7 kernel: w_eff = mk + noise*(noise_eps - mean(noise_eps))
__global__ void GaussianConvBlur_wprep(const float* __restrict__ weight,
                                       const float* __restrict__ noise,
                                       const float* __restrict__ noise_eps,
                                       float* __restrict__ wf) {
    int tid = threadIdx.x;
    if (tid < KS * KS) {
        float m = 0.f;
        #pragma unroll
        for (int i = 0; i < KS * KS; ++i) m += noise_eps[i];
        m *= (1.0f / (KS * KS));
        wf[tid] = weight[tid] + noise[0] * (noise_eps[tid] - m);
    }
}

// LDS-free depthwise 7x7: ring-8 fp32 accumulators; ONE aligned float4 load
// per step, prefetched 2 steps ahead (4-buffer ring); horizontal halo via
// cross-lane shfl of the aligned data (no halo loads at all).
__global__ __launch_bounds__(256) void GaussianConvBlur_conv(
        const float* __restrict__ in,
        const float* __restrict__ wfg,
        float* __restrict__ out) {
    const int lane = threadIdx.x & 63;
    const int wid  = threadIdx.x >> 6;

    const int plane = blockIdx.x >> 2;          // 4 blocks per plane
    const int sblk  = blockIdx.x & 3;
    const int s0    = __builtin_amdgcn_readfirstlane((sblk * WPB + wid) * STRIP);

    const float* __restrict__ src = in  + (size_t)plane * (H * W);
    float*       __restrict__ dst = out + (size_t)plane * (H * W);

    // Pin the 49 uniform weights to SGPRs
    float wf[KS * KS];
    #pragma unroll
    for (int i = 0; i < KS * KS; ++i)
        wf[i] = __int_as_float(__builtin_amdgcn_readfirstlane(__float_as_int(wfg[i])));

    const int x4 = lane << 2;                   // aligned offset (floats)
    const bool ln0  = (lane == 0);
    const bool ln63 = (lane == 63);

    float4 acc[8];
    #pragma unroll
    for (int i = 0; i < 8; ++i) acc[i] = make_float4(0.f, 0.f, 0.f, 0.f);

    float4 pm[4];                               // depth-2 prefetch ring

    #define LOADROW(REL, P) do {                                          \
        int ri_  = s0 - 3 + (REL);                                        \
        int ric_ = ri_ < 0 ? 0 : (ri_ > (H - 1) ? (H - 1) : ri_);         \
        pm[P] = *(const float4*)(src + ric_ * W + x4);                    \
    } while (0)

    #define STEPBODY(REL, U, PF) do {                                     \
        if (PF) LOADROW((REL) + 2, ((U) + 2) & 3);                        \
        const int ri = s0 - 3 + (REL);        /* uniform (SGPR) */        \
        if (ri >= 0 && ri < H) {              /* valid row: accumulate */ \
            float4 r1 = pm[(U) & 3];                                      \
            /* horizontal halo from neighbor lanes (no loads) */          \
            float hl1 = __shfl_up(r1.y, 1, 64);                           \
            float hl2 = __shfl_up(r1.z, 1, 64);                           \
            float hl3 = __shfl_up(r1.w, 1, 64);                           \
            float hr0 = __shfl_down(r1.x, 1, 64);                         \
            float hr1 = __shfl_down(r1.y, 1, 64);                         \
            float hr2 = __shfl_down(r1.z, 1, 64);                         \
            float s[10];                                                  \
            s[0] = ln0  ? 0.f : hl1;                                      \
            s[1] = ln0  ? 0.f : hl2;                                      \
            s[2] = ln0  ? 0.f : hl3;                                      \
            s[3] = r1.x; s[4] = r1.y; s[5] = r1.z; s[6] = r1.w;           \
            s[7] = ln63 ? 0.f : hr0;                                      \
            s[8] = ln63 ? 0.f : hr1;                                      \
            s[9] = ln63 ? 0.f : hr2;                                      \
            _Pragma("unroll")                                             \
            for (int j = 0; j < 7; ++j) {                                 \
                const int slot = ((U) + j) & 7;    /* compile-time */     \
                const int ky   = 6 - j;                                   \
                _Pragma("unroll")                                         \
                for (int kx = 0; kx < 7; ++kx) {                          \
                    const float wv = wf[ky * 7 + kx];                     \
                    acc[slot].x = fmaf(wv, s[kx],     acc[slot].x);       \
                    acc[slot].y = fmaf(wv, s[kx + 1], acc[slot].y);       \
                    acc[slot].z = fmaf(wv, s[kx + 2], acc[slot].z);       \
                    acc[slot].w = fmaf(wv, s[kx + 3], acc[slot].w);       \
                }                                                         \
            }                                                             \
        }                                                                 \
        const int o = ri - 3;            /* this row completes now */     \
        if (o >= s0) *(float4*)(dst + o * W + x4) = acc[(U) & 7];         \
        acc[(U) & 7] = make_float4(0.f, 0.f, 0.f, 0.f);                   \
    } while (0)

    LOADROW(0, 0);
    LOADROW(1, 1);

    for (int g = 0; g < 2; ++g) {         // rel = 0..15  (8 | 4-ring ok: 8%4==0)
        #pragma unroll
        for (int u = 0; u < 8; ++u) STEPBODY(g * 8 + u, u, true);
    }
    #pragma unroll
    for (int u = 0; u < 6; ++u)           // rel = 16..21; last load is rel 21
        STEPBODY(16 + u, u, (u < 4));

    #undef LOADROW
    #undef STEPBODY
}

extern "C" void kernel_launch(void* const* d_in, const int* in_sizes, int n_in,
                              void* d_out, int out_size, void* d_ws, size_t ws_size,
                              hipStream_t stream) {
    const float* x         = (const float*)d_in[0];  // (16,64,256,256)
    const float* weight    = (const float*)d_in[1];  // (64,64,7,7)
    const float* noise     = (const float*)d_in[2];  // scalar
    const float* noise_eps = (const float*)d_in[3];  // (7,7)
    float*       out       = (float*)d_out;
    float*       wf        = (float*)d_ws;           // 49 floats scratch

    GaussianConvBlur_wprep<<<1, 64, 0, stream>>>(weight, noise, noise_eps, wf);

    const int planes = 16 * 64;                       // 1024 planes
    GaussianConvBlur_conv<<<planes * 4, 256, 0, stream>>>(x, wf, out);
}

// Round 7
// 111.670 us; speedup vs baseline: 1.3675x; 1.0653x over previous
//
#include <hip/hip_runtime.h>

#define KS    7
#define H     256
#define W     256
#define STRIP 16                 // output rows per wave
#define WPB   4                  // waves per block (block covers 64 rows)
#define NSTEP (STRIP + KS - 1)   // 22 input rows per strip

typedef float vf4 __attribute__((ext_vector_type(4)));  // native clang vector

// Build effective 7x7 kernel: w_eff = mk + noise*(noise_eps - mean(noise_eps))
__global__ void GaussianConvBlur_wprep(const float* __restrict__ weight,
                                       const float* __restrict__ noise,
                                       const float* __restrict__ noise_eps,
                                       float* __restrict__ wf) {
    int tid = threadIdx.x;
    if (tid < KS * KS) {
        float m = 0.f;
        #pragma unroll
        for (int i = 0; i < KS * KS; ++i) m += noise_eps[i];
        m *= (1.0f / (KS * KS));
        wf[tid] = weight[tid] + noise[0] * (noise_eps[tid] - m);
    }
}

// LDS-free depthwise 7x7: ring-8 fp32 accumulators; ONE aligned float4 load
// per step prefetched 3 steps ahead (4-buffer ring); horizontal halo via
// cross-lane shfl; NON-TEMPORAL output stores keep the L3 for the input.
__global__ __launch_bounds__(256) void GaussianConvBlur_conv(
        const float* __restrict__ in,
        const float* __restrict__ wfg,
        float* __restrict__ out) {
    const int lane = threadIdx.x & 63;
    const int wid  = threadIdx.x >> 6;

    const int plane = blockIdx.x >> 2;          // 4 blocks per plane
    const int sblk  = blockIdx.x & 3;
    const int s0    = __builtin_amdgcn_readfirstlane((sblk * WPB + wid) * STRIP);

    const float* __restrict__ src = in  + (size_t)plane * (H * W);
    float*       __restrict__ dst = out + (size_t)plane * (H * W);

    // Pin the 49 uniform weights to SGPRs
    float wf[KS * KS];
    #pragma unroll
    for (int i = 0; i < KS * KS; ++i)
        wf[i] = __int_as_float(__builtin_amdgcn_readfirstlane(__float_as_int(wfg[i])));

    const int x4 = lane << 2;                   // aligned offset (floats)
    const bool ln0  = (lane == 0);
    const bool ln63 = (lane == 63);

    vf4 acc[8];
    #pragma unroll
    for (int i = 0; i < 8; ++i) acc[i] = (vf4)(0.f);

    vf4 pm[4];                                  // depth-3 prefetch ring

    #define LOADROW(REL, P) do {                                          \
        int ri_  = s0 - 3 + (REL);                                        \
        int ric_ = ri_ < 0 ? 0 : (ri_ > (H - 1) ? (H - 1) : ri_);         \
        pm[P] = *(const vf4*)(src + ric_ * W + x4);                       \
    } while (0)

    #define STEPBODY(REL, U, PF) do {                                     \
        if (PF) LOADROW((REL) + 3, ((U) + 3) & 3);                        \
        const int ri = s0 - 3 + (REL);        /* uniform (SGPR) */        \
        if (ri >= 0 && ri < H) {              /* valid row: accumulate */ \
            vf4 r1 = pm[(U) & 3];                                         \
            /* horizontal halo from neighbor lanes (no loads) */          \
            float hl1 = __shfl_up(r1.y, 1, 64);                           \
            float hl2 = __shfl_up(r1.z, 1, 64);                           \
            float hl3 = __shfl_up(r1.w, 1, 64);                           \
            float hr0 = __shfl_down(r1.x, 1, 64);                         \
            float hr1 = __shfl_down(r1.y, 1, 64);                         \
            float hr2 = __shfl_down(r1.z, 1, 64);                         \
            float s[10];                                                  \
            s[0] = ln0  ? 0.f : hl1;                                      \
            s[1] = ln0  ? 0.f : hl2;                                      \
            s[2] = ln0  ? 0.f : hl3;                                      \
            s[3] = r1.x; s[4] = r1.y; s[5] = r1.z; s[6] = r1.w;           \
            s[7] = ln63 ? 0.f : hr0;                                      \
            s[8] = ln63 ? 0.f : hr1;                                      \
            s[9] = ln63 ? 0.f : hr2;                                      \
            _Pragma("unroll")                                             \
            for (int j = 0; j < 7; ++j) {                                 \
                const int slot = ((U) + j) & 7;    /* compile-time */     \
                const int ky   = 6 - j;                                   \
                _Pragma("unroll")                                         \
                for (int kx = 0; kx < 7; ++kx) {                          \
                    const float wv = wf[ky * 7 + kx];                     \
                    acc[slot].x = fmaf(wv, s[kx],     acc[slot].x);       \
                    acc[slot].y = fmaf(wv, s[kx + 1], acc[slot].y);       \
                    acc[slot].z = fmaf(wv, s[kx + 2], acc[slot].z);       \
                    acc[slot].w = fmaf(wv, s[kx + 3], acc[slot].w);       \
                }                                                         \
            }                                                             \
        }                                                                 \
        const int o = ri - 3;            /* this row completes now */     \
        if (o >= s0)                                                      \
            __builtin_nontemporal_store(acc[(U) & 7],                     \
                                        (vf4*)(dst + o * W + x4));        \
        acc[(U) & 7] = (vf4)(0.f);                                        \
    } while (0)

    LOADROW(0, 0);
    LOADROW(1, 1);
    LOADROW(2, 2);

    for (int g = 0; g < 2; ++g) {         // rel = 0..15 (8-unroll, ring%4==0)
        #pragma unroll
        for (int u = 0; u < 8; ++u) STEPBODY(g * 8 + u, u, true);
    }
    #pragma unroll
    for (int u = 0; u < 6; ++u)           // rel = 16..21; last load is rel 21
        STEPBODY(16 + u, u, (u < 3));

    #undef LOADROW
    #undef STEPBODY
}

extern "C" void kernel_launch(void* const* d_in, const int* in_sizes, int n_in,
                              void* d_out, int out_size, void* d_ws, size_t ws_size,
                              hipStream_t stream) {
    const float* x         = (const float*)d_in[0];  // (16,64,256,256)
    const float* weight    = (const float*)d_in[1];  // (64,64,7,7)
    const float* noise     = (const float*)d_in[2];  // scalar
    const float* noise_eps = (const float*)d_in[3];  // (7,7)
    float*       out       = (float*)d_out;
    float*       wf        = (float*)d_ws;           // 49 floats scratch

    GaussianConvBlur_wprep<<<1, 64, 0, stream>>>(weight, noise, noise_eps, wf);

    const int planes = 16 * 64;                       // 1024 planes
    GaussianConvBlur_conv<<<planes * 4, 256, 0, stream>>>(x, wf, out);
}